// Round 4
// baseline (2397.157 us; speedup 1.0000x reference)
//
#include <hip/hip_runtime.h>
#include <math.h>

// Problem constants: B=16, T=64, V=50257, E=512, H=1024, L=2
#define Bc 16
#define Tc 64
#define Vc 50257
#define Ec 512
#define Hc 1024
#define SCAN_BLOCKS 256

typedef __attribute__((ext_vector_type(4))) float f32x4;
typedef __attribute__((ext_vector_type(8))) __bf16 bf16x8;

__device__ __forceinline__ float dot4(float4 a, float4 b) {
    return a.x * b.x + a.y * b.y + a.z * b.z + a.w * b.w;
}
__device__ __forceinline__ float sigm(float x) { return 1.0f / (1.0f + expf(-x)); }

// round-to-nearest-even float -> bf16 bits (finite inputs)
__device__ __forceinline__ unsigned short f2b(float f) {
    unsigned u = __float_as_uint(f);
    unsigned r = u + 0x7fffu + ((u >> 16) & 1u);
    return (unsigned short)(r >> 16);
}
__device__ __forceinline__ float b2f(unsigned short b) {
    return __uint_as_float(((unsigned)b) << 16);
}

// ---------------------------------------------------------------------------
// split fp32 -> (hi, lo) bf16 pair, 4 elements/thread
// ---------------------------------------------------------------------------
__global__ __launch_bounds__(256) void split_bf16_4(const float4* __restrict__ x,
                                                    ushort4* __restrict__ hi,
                                                    ushort4* __restrict__ lo, int n4) {
    int i = blockIdx.x * 256 + threadIdx.x;
    for (; i < n4; i += gridDim.x * 256) {
        float4 v = x[i];
        ushort4 h, l;
        h.x = f2b(v.x); l.x = f2b(v.x - b2f(h.x));
        h.y = f2b(v.y); l.y = f2b(v.y - b2f(h.y));
        h.z = f2b(v.z); l.z = f2b(v.z - b2f(h.z));
        h.w = f2b(v.w); l.w = f2b(v.w - b2f(h.w));
        hi[i] = h;
        lo[i] = l;
    }
}

// ---------------------------------------------------------------------------
// Build X0 (T*B, 2E): row m=t*B+b; cols [0,512)=emb[helper[b,t]], [512,1024)=init[b]
// ---------------------------------------------------------------------------
__global__ __launch_bounds__(256) void build_x0(const float* __restrict__ emb,
                                                const int* __restrict__ helper,
                                                const float* __restrict__ init,
                                                float* __restrict__ X0) {
    int idx = blockIdx.x * 256 + threadIdx.x;
    const int total = Tc * Bc * 1024;
    for (int i = idx; i < total; i += gridDim.x * 256) {
        int m = i >> 10;
        int c = i & 1023;
        int t = m >> 4;
        int b = m & 15;
        float v;
        if (c < 512) {
            int w = helper[b * Tc + t];
            v = emb[(size_t)w * Ec + c];
        } else {
            v = init[b * Ec + (c - 512)];
        }
        X0[i] = v;
    }
}

// ---------------------------------------------------------------------------
// h0 one-step GRU with zero initial state. dup=1 -> input row is [init;init].
// Emits fp32 h0 (for chaining) AND bf16 hi/lo into ys slot 0 (for the scan).
// ---------------------------------------------------------------------------
__global__ __launch_bounds__(256) void h0_layer(const float* __restrict__ xin,
                                                const float* __restrict__ Wih,
                                                const float* __restrict__ bih,
                                                const float* __restrict__ bhh,
                                                float* __restrict__ h0out,
                                                unsigned short* __restrict__ ysh,
                                                unsigned short* __restrict__ ysl,
                                                int dup) {
    __shared__ float xs[1024];
    int b = blockIdx.x >> 2;
    int hseg = blockIdx.x & 3;
    int tid = threadIdx.x;
    for (int i = tid; i < 1024; i += 256)
        xs[i] = dup ? xin[b * 512 + (i & 511)] : xin[b * 1024 + i];
    __syncthreads();
    int hidx = hseg * 256 + tid;
    const float* wr = Wih + (size_t)hidx * 1024;
    const float* wz = Wih + (size_t)(Hc + hidx) * 1024;
    const float* wn = Wih + (size_t)(2 * Hc + hidx) * 1024;
    float ar = 0.f, az = 0.f, an = 0.f;
    for (int k = 0; k < 1024; k += 4) {
        float4 x4 = *(const float4*)&xs[k];
        ar += dot4(*(const float4*)&wr[k], x4);
        az += dot4(*(const float4*)&wz[k], x4);
        an += dot4(*(const float4*)&wn[k], x4);
    }
    float r = sigm(ar + bih[hidx] + bhh[hidx]);
    float z = sigm(az + bih[Hc + hidx] + bhh[Hc + hidx]);
    float n = tanhf(an + bih[2 * Hc + hidx] + r * bhh[2 * Hc + hidx]);
    float h = (1.f - z) * n;  // h_old = 0
    h0out[b * Hc + hidx] = h;
    unsigned short hb = f2b(h);
    ysh[b * 1024 + hidx] = hb;
    ysl[b * 1024 + hidx] = f2b(h - b2f(hb));
}

// ---------------------------------------------------------------------------
// MFMA-based 64-step GRU scan. 256 blocks x 64 threads (ONE wave per block).
// Block k owns h-indices [4k,4k+4) = 12 gate-rows (gr = gate*4+hl, gate-major).
// W_hh rows split fp32->bf16 hi/lo ONCE into XOR-swizzled LDS (64 KB).
// Per round t: the wave loads the full h[t] slice (16 b x 1024 k, bf16 hi/lo)
// with PLAIN cacheable 16B loads — slot t lines are written exactly once
// (sc0/sc1 write-through stores, drained by vmcnt(0) BEFORE the barrier) and
// only read after the barrier, so no L1/L2 can hold a stale copy (addresses
// untouched earlier in this kernel; dispatch-boundary acquire invalidates
// per-XCD L2 across launches). First touch per XCD pulls from L3, the other
// ~31 blocks hit local L2/L1: ~8x less L3 burst than the old 8B agent-atomic
// loads. A-frags (weights) come from LDS; 4-pass split product (hh+hl+lh+ll,
// rep error ~2^-17) over 32 k-tiles: 128 x mfma_f32_16x16x32_bf16. D[gr][b]
// lands at lane(col=b, row=quad*4+reg); tiny LDS transpose hands all 12 gate
// values for batch b to lane b, which applies GRU gate math in fp32, keeps
// h_old in registers, stores h[t+1] as bf16 hi/lo (8B agent-scope atomic
// stores, UNCHANGED). Inter-block sync: proven 16-leaf+root tree barrier via
// agent-scope relaxed atomics + s_sleep poll.
// ---------------------------------------------------------------------------
__global__ __launch_bounds__(64, 1) void gru_scan_mfma(
    const float* __restrict__ xp, const float* __restrict__ Whh,
    const float* __restrict__ bhh, unsigned short* __restrict__ ysh,
    unsigned short* __restrict__ ysl, unsigned* __restrict__ bar) {
    extern __shared__ unsigned short Wlo[];   // [16*1024] 32 KB (dynamic)
    __shared__ unsigned short Whi[16][1024];  // 32 KB
    __shared__ float dxc[16][16];             // D transpose scratch
    const int lane = threadIdx.x;
    const int g0 = blockIdx.x * 4;
    const int brow = lane & 15;  // A-row (gr) for LDS reads, B-row (b) for h
    const int kq = lane >> 4;    // k-quadrant within a 32-wide k-tile

    // stage 12 weight rows (gr = gate*4+hl), split to hi/lo, XOR-swizzled so
    // a-frag ds_read_b128 across rows 0-15 is bank-conflict-free (G4 fix:
    // byte ^= (row&7)<<4; row stride 2048B would otherwise be 16-way).
    for (int i = lane; i < 12 * 256; i += 64) {
        int r = i >> 8, c = i & 255;
        size_t wrow = (size_t)((r >> 2) * Hc + g0 + (r & 3)) * Hc;
        float4 w4 = *(const float4*)&Whh[wrow + c * 4];
        ushort4 h4, l4;
        h4.x = f2b(w4.x); l4.x = f2b(w4.x - b2f(h4.x));
        h4.y = f2b(w4.y); l4.y = f2b(w4.y - b2f(h4.y));
        h4.z = f2b(w4.z); l4.z = f2b(w4.z - b2f(h4.z));
        h4.w = f2b(w4.w); l4.w = f2b(w4.w - b2f(h4.w));
        int bo = (c * 8) ^ ((r & 7) << 4);
        *(ushort4*)((char*)&Whi[r][0] + bo) = h4;
        *(ushort4*)((char*)&Wlo[r * 1024] + bo) = l4;
    }
    ushort4 z4 = {0, 0, 0, 0};
    for (int i = lane; i < 4 * 256; i += 64) {  // pad rows 12-15 = 0
        int r = 12 + (i >> 8), c = i & 255;
        ((ushort4*)&Whi[r][0])[c] = z4;
        ((ushort4*)&Wlo[r * 1024])[c] = z4;
    }

    float bh[12];
#pragma unroll
    for (int r = 0; r < 12; ++r) bh[r] = bhh[(r >> 2) * Hc + g0 + (r & 3)];

    // hold init from slot 0 (hi+lo reconstruct), lanes 0-15 use it
    float hold[4];
    {
        const unsigned long long* s0h =
            (const unsigned long long*)ysh + (size_t)brow * 256 + blockIdx.x;
        const unsigned long long* s0l =
            (const unsigned long long*)ysl + (size_t)brow * 256 + blockIdx.x;
        union { unsigned long long u; ushort4 s; } ch, cl;
        ch.u = *s0h;
        cl.u = *s0l;
        hold[0] = b2f(ch.s.x) + b2f(cl.s.x);
        hold[1] = b2f(ch.s.y) + b2f(cl.s.y);
        hold[2] = b2f(ch.s.z) + b2f(cl.s.z);
        hold[3] = b2f(ch.s.w) + b2f(cl.s.w);
    }
    __syncthreads();

    const char* wha = (const char*)&Whi[0][0] + brow * 2048;
    const char* wla = (const char*)Wlo + brow * 2048;
    const int swz = (brow & 7) << 4;

    unsigned* leaf = bar + (blockIdx.x & 15) * 32;  // 128 B apart
    unsigned* root = bar + 512;

    for (int t = 0; t < Tc; ++t) {
        // B-frag h loads: plain cacheable 16B loads (see header comment for
        // the coherence argument). Row (t*16+brow) is 2048B of k; lane grabs
        // kq*16 + kt*64 byte chunks — hi and lo streams.
        const char* pbh = (const char*)ysh + (size_t)(t * 16 + brow) * 2048 + kq * 16;
        const char* pbl = (const char*)ysl + (size_t)(t * 16 + brow) * 2048 + kq * 16;
        bf16x8 hv[32], lv[32];
#pragma unroll
        for (int kt = 0; kt < 32; ++kt) {
            hv[kt] = *(const bf16x8*)(pbh + kt * 64);
            lv[kt] = *(const bf16x8*)(pbl + kt * 64);
        }
        // xp gate values for (t, b) — plain loads (xp static since GEMM)
        const float* xrow = xp + (size_t)(t * 16 + brow) * 3072 + g0;
        f32x4 xgr = *(const f32x4*)&xrow[0];
        f32x4 xgz = *(const f32x4*)&xrow[1024];
        f32x4 xgn = *(const f32x4*)&xrow[2048];

        f32x4 zz = {0.f, 0.f, 0.f, 0.f};
        f32x4 acc[4];
        acc[0] = zz; acc[1] = zz; acc[2] = zz; acc[3] = zz;
#pragma unroll
        for (int kt = 0; kt < 32; ++kt) {
            bf16x8 ah = *(const bf16x8*)(wha + ((kt * 64 + kq * 16) ^ swz));
            bf16x8 al = *(const bf16x8*)(wla + ((kt * 64 + kq * 16) ^ swz));
            acc[kt & 3] = __builtin_amdgcn_mfma_f32_16x16x32_bf16(ah, hv[kt],
                                                                  acc[kt & 3], 0, 0, 0);
            acc[kt & 3] = __builtin_amdgcn_mfma_f32_16x16x32_bf16(ah, lv[kt],
                                                                  acc[kt & 3], 0, 0, 0);
            acc[kt & 3] = __builtin_amdgcn_mfma_f32_16x16x32_bf16(al, hv[kt],
                                                                  acc[kt & 3], 0, 0, 0);
            acc[kt & 3] = __builtin_amdgcn_mfma_f32_16x16x32_bf16(al, lv[kt],
                                                                  acc[kt & 3], 0, 0, 0);
        }
        f32x4 d = acc[0] + acc[1] + acc[2] + acc[3];
        // transpose D[gr][b] -> lane b via LDS (quad q holds gr = q*4+reg)
        if (kq < 3) *(f32x4*)&dxc[brow][kq * 4] = d;
        __syncthreads();  // 1-wave: just lgkmcnt drain

        if (lane < 16) {
            f32x4 ghr = *(const f32x4*)&dxc[lane][0];
            f32x4 ghz = *(const f32x4*)&dxc[lane][4];
            f32x4 ghn = *(const f32x4*)&dxc[lane][8];
            union { unsigned long long u; ushort4 s; } ph, pl;
            float hn4[4];
#pragma unroll
            for (int hl = 0; hl < 4; ++hl) {
                float r_ = sigm(xgr[hl] + ghr[hl] + bh[hl]);
                float z_ = sigm(xgz[hl] + ghz[hl] + bh[4 + hl]);
                float n_ = tanhf(xgn[hl] + r_ * (ghn[hl] + bh[8 + hl]));
                float h = (1.f - z_) * n_ + z_ * hold[hl];
                hold[hl] = h;
                hn4[hl] = h;
            }
            ph.s.x = f2b(hn4[0]); pl.s.x = f2b(hn4[0] - b2f(ph.s.x));
            ph.s.y = f2b(hn4[1]); pl.s.y = f2b(hn4[1] - b2f(ph.s.y));
            ph.s.z = f2b(hn4[2]); pl.s.z = f2b(hn4[2] - b2f(ph.s.z));
            ph.s.w = f2b(hn4[3]); pl.s.w = f2b(hn4[3] - b2f(ph.s.w));
            unsigned long long* dh = (unsigned long long*)ysh +
                                     (size_t)((t + 1) * 16 + lane) * 256 + blockIdx.x;
            unsigned long long* dl = (unsigned long long*)ysl +
                                     (size_t)((t + 1) * 16 + lane) * 256 + blockIdx.x;
            __hip_atomic_store(dh, ph.u, __ATOMIC_RELAXED, __HIP_MEMORY_SCOPE_AGENT);
            __hip_atomic_store(dl, pl.u, __ATOMIC_RELAXED, __HIP_MEMORY_SCOPE_AGENT);
        }

        if (t < Tc - 1) {
            asm volatile("s_waitcnt vmcnt(0)" ::: "memory");  // h stores drained
            if (lane == 0) {
                unsigned old = __hip_atomic_fetch_add(leaf, 1u, __ATOMIC_RELAXED,
                                                      __HIP_MEMORY_SCOPE_AGENT);
                if (old == (unsigned)(t * 16 + 15))
                    __hip_atomic_fetch_add(root, 1u, __ATOMIC_RELAXED,
                                           __HIP_MEMORY_SCOPE_AGENT);
            }
            unsigned tgt = (unsigned)((t + 1) * 16);
            while (__hip_atomic_load(root, __ATOMIC_RELAXED,
                                     __HIP_MEMORY_SCOPE_AGENT) < tgt)
                __builtin_amdgcn_s_sleep(1);
            asm volatile("" ::: "memory");
        }
    }
}

// ---------------------------------------------------------------------------
// Split-bf16 MFMA GEMM (fp32-accurate): C = act( A @ B^T + bias ), where
// A = Ah + Al, B = Bh + Bl and C = Ah Bh + Ah Bl + Al Bh (3 phases).
// 128x128 tile, BK=32, 4 waves in 2x2, 16x16x32 bf16 MFMA.
// remap=1: output row m=t*B+b stored at row b*T+t. N edge guarded.
// ---------------------------------------------------------------------------
#define GLD_LDS16(g, l)                                                        \
    __builtin_amdgcn_global_load_lds(                                          \
        (const __attribute__((address_space(1))) unsigned int*)(g),            \
        (__attribute__((address_space(3))) unsigned int*)(l), 16, 0, 0)

__global__ __launch_bounds__(256) void mfma_gemm_split(
    const unsigned short* __restrict__ Ah, const unsigned short* __restrict__ Al,
    const unsigned short* __restrict__ Bh, const unsigned short* __restrict__ Bl,
    const float* __restrict__ bias, float* __restrict__ C, int N, int K, int ldc,
    int act, int remap) {
    __shared__ __align__(16) unsigned short As[128 * 32];  // [m][k] 8 KB
    __shared__ __align__(16) unsigned short Bs[128 * 32];  // [n][k] 8 KB
    int tid = threadIdx.x;
    int m0 = blockIdx.y * 128, n0 = blockIdx.x * 128;
    int wave = tid >> 6, lane = tid & 63;
    int mh = (wave >> 1) * 64, nh = (wave & 1) * 64;
    int rlane = lane & 15, k8 = (lane >> 4) * 8;

    f32x4 zero = {0.f, 0.f, 0.f, 0.f};
    f32x4 acc[4][4];
#pragma unroll
    for (int i = 0; i < 4; ++i)
#pragma unroll
        for (int j = 0; j < 4; ++j) acc[i][j] = zero;

    const unsigned short* Ap[3] = {Ah, Al, Ah};
    const unsigned short* Bp[3] = {Bh, Bh, Bl};

    int c0 = tid, c1 = tid + 256;
    int ar0 = m0 + (c0 >> 2), ak0 = (c0 & 3) * 8;
    int ar1 = m0 + (c1 >> 2), ak1 = (c1 & 3) * 8;
    int br0 = n0 + (c0 >> 2);
    int br1 = n0 + (c1 >> 2);
    if (br0 >= N) br0 = N - 1;
    if (br1 >= N) br1 = N - 1;

    for (int ph = 0; ph < 3; ++ph) {
        const unsigned short* Ab = Ap[ph];
        const unsigned short* Bb = Bp[ph];
        for (int kt = 0; kt < K; kt += 32) {
            GLD_LDS16(&Ab[(size_t)ar0 * K + kt + ak0], &As[c0 * 8]);
            GLD_LDS16(&Ab[(size_t)ar1 * K + kt + ak1], &As[c1 * 8]);
            GLD_LDS16(&Bb[(size_t)br0 * K + kt + ak0], &Bs[c0 * 8]);
            GLD_LDS16(&Bb[(size_t)br1 * K + kt + ak1], &Bs[c1 * 8]);
            __syncthreads();
            bf16x8 a[4], b[4];
#pragma unroll
            for (int f = 0; f < 4; ++f)
                a[f] = *(const bf16x8*)&As[(mh + f * 16 + rlane) * 32 + k8];
#pragma unroll
            for (int f = 0; f < 4; ++f)
                b[f] = *(const bf16x8*)&Bs[(nh + f * 16 + rlane) * 32 + k8];
#pragma unroll
            for (int mf = 0; mf < 4; ++mf)
#pragma unroll
                for (int nf = 0; nf < 4; ++nf)
                    acc[mf][nf] = __builtin_amdgcn_mfma_f32_16x16x32_bf16(
                        a[mf], b[nf], acc[mf][nf], 0, 0, 0);
            __syncthreads();
        }
    }

    int quad = lane >> 4;
#pragma unroll
    for (int nf = 0; nf < 4; ++nf) {
        int n = n0 + nh + nf * 16 + rlane;
        if (n >= N) continue;
        float bv = bias ? bias[n] : 0.f;
#pragma unroll
        for (int mf = 0; mf < 4; ++mf) {
#pragma unroll
            for (int r = 0; r < 4; ++r) {
                int m = m0 + mh + mf * 16 + quad * 4 + r;
                float x = acc[mf][nf][r] + bv;
                if (act) x = tanhf(x);
                int orow = remap ? ((m & 15) * Tc + (m >> 4)) : m;
                C[(size_t)orow * ldc + n] = x;
            }
        }
    }
}

// ---------------------------------------------------------------------------
extern "C" void kernel_launch(void* const* d_in, const int* in_sizes, int n_in,
                              void* d_out, int out_size, void* d_ws, size_t ws_size,
                              hipStream_t stream) {
    const float* init   = (const float*)d_in[0];
    const int*   helper = (const int*)d_in[1];
    const float* emb    = (const float*)d_in[2];
    const float* W_ih0  = (const float*)d_in[3];
    const float* W_hh0  = (const float*)d_in[4];
    const float* b_ih0  = (const float*)d_in[5];
    const float* b_hh0  = (const float*)d_in[6];
    const float* W_ih1  = (const float*)d_in[7];
    const float* W_hh1  = (const float*)d_in[8];
    const float* b_ih1  = (const float*)d_in[9];
    const float* b_hh1  = (const float*)d_in[10];
    const float* Wc_w   = (const float*)d_in[11];
    const float* Wc_b   = (const float*)d_in[12];
    float* out = (float*)d_out;

    const int embN = Vc * Ec;
    const size_t ysN = (size_t)65 * 16 * 1024;  // bf16 elements per ys stream

    char* p = (char*)d_ws;
    auto alloc = [&](size_t bytes) {
        char* r = p;
        p += (bytes + 255) & ~(size_t)255;
        return r;
    };
    float* X0   = (float*)alloc((size_t)1048576 * 4);
    float* xp0  = (float*)alloc((size_t)3145728 * 4);
    float* xp1  = (float*)alloc((size_t)3145728 * 4);
    float* fin  = (float*)alloc((size_t)524288 * 4);
    float* h00  = (float*)alloc((size_t)16384 * 4);
    float* h01  = (float*)alloc((size_t)16384 * 4);
    unsigned* bar = (unsigned*)alloc(8192);
    unsigned short* embh = (unsigned short*)alloc((size_t)embN * 2);
    unsigned short* embl = (unsigned short*)alloc((size_t)embN * 2);
    unsigned short* X0h  = (unsigned short*)alloc((size_t)1048576 * 2);
    unsigned short* X0l  = (unsigned short*)alloc((size_t)1048576 * 2);
    unsigned short* Wi0h = (unsigned short*)alloc((size_t)3145728 * 2);
    unsigned short* Wi0l = (unsigned short*)alloc((size_t)3145728 * 2);
    unsigned short* Wi1h = (unsigned short*)alloc((size_t)3145728 * 2);
    unsigned short* Wi1l = (unsigned short*)alloc((size_t)3145728 * 2);
    unsigned short* Wch  = (unsigned short*)alloc((size_t)524288 * 2);
    unsigned short* Wcl  = (unsigned short*)alloc((size_t)524288 * 2);
    unsigned short* ys0h = (unsigned short*)alloc(ysN * 2);
    unsigned short* ys0l = (unsigned short*)alloc(ysN * 2);
    unsigned short* ys1h = (unsigned short*)alloc(ysN * 2);
    unsigned short* ys1l = (unsigned short*)alloc(ysN * 2);
    unsigned short* finh = (unsigned short*)alloc((size_t)524288 * 2);
    unsigned short* finl = (unsigned short*)alloc((size_t)524288 * 2);

    hipMemsetAsync(bar, 0, 8192, stream);

    auto split = [&](const float* src, unsigned short* h, unsigned short* l, int n) {
        int n4 = n / 4;
        int grid = (n4 + 255) / 256;
        if (grid > 4096) grid = 4096;
        split_bf16_4<<<grid, 256, 0, stream>>>((const float4*)src, (ushort4*)h,
                                               (ushort4*)l, n4);
    };

    split(emb, embh, embl, embN);
    split(W_ih0, Wi0h, Wi0l, 3145728);
    split(W_ih1, Wi1h, Wi1l, 3145728);
    split(Wc_w, Wch, Wcl, 524288);

    // h0 chain: layer0 (fp32 out + ys0 slot 0 hi/lo), layer1 (ys1 slot 0)
    h0_layer<<<64, 256, 0, stream>>>(init, W_ih0, b_ih0, b_hh0, h00, ys0h, ys0l, 1);
    h0_layer<<<64, 256, 0, stream>>>(h00, W_ih1, b_ih1, b_hh1, h01, ys1h, ys1l, 0);

    build_x0<<<1024, 256, 0, stream>>>(emb, helper, init, X0);
    split(X0, X0h, X0l, 1048576);
    mfma_gemm_split<<<dim3(24, 8), 256, 0, stream>>>(X0h, X0l, Wi0h, Wi0l, b_ih0,
                                                     xp0, 3072, 1024, 3072, 0, 0);

    // layer-0 scan (MFMA recurrent MAC, emits ys0 hi/lo directly)
    gru_scan_mfma<<<SCAN_BLOCKS, 64, 32768, stream>>>(xp0, W_hh0, b_hh0, ys0h, ys0l,
                                                      bar);

    // xp1 GEMM consumes ys0 hi/lo natively (no split kernel needed)
    mfma_gemm_split<<<dim3(24, 8), 256, 0, stream>>>(ys0h + 16384, ys0l + 16384,
                                                     Wi1h, Wi1l, b_ih1, xp1, 3072,
                                                     1024, 3072, 0, 0);

    gru_scan_mfma<<<SCAN_BLOCKS, 64, 32768, stream>>>(xp1, W_hh1, b_hh1, ys1h, ys1l,
                                                      bar + 1024);

    mfma_gemm_split<<<dim3(4, 8), 256, 0, stream>>>(ys1h + 16384, ys1l + 16384,
                                                    Wch, Wcl, Wc_b, fin, 512, 1024,
                                                    512, 1, 0);

    split(fin, finh, finl, 524288);
    mfma_gemm_split<<<dim3((Vc + 127) / 128, 8), 256, 0, stream>>>(
        finh, finl, embh, embl, nullptr, out, Vc, 512, Vc, 0, 1);
}

// Round 5
// 2135.532 us; speedup vs baseline: 1.1225x; 1.1225x over previous
//
#include <hip/hip_runtime.h>
#include <math.h>

// Problem constants: B=16, T=64, V=50257, E=512, H=1024, L=2
#define Bc 16
#define Tc 64
#define Vc 50257
#define Ec 512
#define Hc 1024
#define SCAN_BLOCKS 256

typedef __attribute__((ext_vector_type(4))) float f32x4;
typedef __attribute__((ext_vector_type(8))) __bf16 bf16x8;

__device__ __forceinline__ float dot4(float4 a, float4 b) {
    return a.x * b.x + a.y * b.y + a.z * b.z + a.w * b.w;
}
__device__ __forceinline__ float sigm(float x) { return 1.0f / (1.0f + expf(-x)); }

// round-to-nearest-even float -> bf16 bits (finite inputs)
__device__ __forceinline__ unsigned short f2b(float f) {
    unsigned u = __float_as_uint(f);
    unsigned r = u + 0x7fffu + ((u >> 16) & 1u);
    return (unsigned short)(r >> 16);
}
__device__ __forceinline__ float b2f(unsigned short b) {
    return __uint_as_float(((unsigned)b) << 16);
}

// ---------------------------------------------------------------------------
// split fp32 -> (hi, lo) bf16 pair, 4 elements/thread
// ---------------------------------------------------------------------------
__global__ __launch_bounds__(256) void split_bf16_4(const float4* __restrict__ x,
                                                    ushort4* __restrict__ hi,
                                                    ushort4* __restrict__ lo, int n4) {
    int i = blockIdx.x * 256 + threadIdx.x;
    for (; i < n4; i += gridDim.x * 256) {
        float4 v = x[i];
        ushort4 h, l;
        h.x = f2b(v.x); l.x = f2b(v.x - b2f(h.x));
        h.y = f2b(v.y); l.y = f2b(v.y - b2f(h.y));
        h.z = f2b(v.z); l.z = f2b(v.z - b2f(h.z));
        h.w = f2b(v.w); l.w = f2b(v.w - b2f(h.w));
        hi[i] = h;
        lo[i] = l;
    }
}

// ---------------------------------------------------------------------------
// Build X0 (T*B, 2E): row m=t*B+b; cols [0,512)=emb[helper[b,t]], [512,1024)=init[b]
// ---------------------------------------------------------------------------
__global__ __launch_bounds__(256) void build_x0(const float* __restrict__ emb,
                                                const int* __restrict__ helper,
                                                const float* __restrict__ init,
                                                float* __restrict__ X0) {
    int idx = blockIdx.x * 256 + threadIdx.x;
    const int total = Tc * Bc * 1024;
    for (int i = idx; i < total; i += gridDim.x * 256) {
        int m = i >> 10;
        int c = i & 1023;
        int t = m >> 4;
        int b = m & 15;
        float v;
        if (c < 512) {
            int w = helper[b * Tc + t];
            v = emb[(size_t)w * Ec + c];
        } else {
            v = init[b * Ec + (c - 512)];
        }
        X0[i] = v;
    }
}

// ---------------------------------------------------------------------------
// h0 one-step GRU with zero initial state. dup=1 -> input row is [init;init].
// Emits fp32 h0 (for chaining) AND bf16 hi/lo into ys slot 0 (for the scan).
// ---------------------------------------------------------------------------
__global__ __launch_bounds__(256) void h0_layer(const float* __restrict__ xin,
                                                const float* __restrict__ Wih,
                                                const float* __restrict__ bih,
                                                const float* __restrict__ bhh,
                                                float* __restrict__ h0out,
                                                unsigned short* __restrict__ ysh,
                                                unsigned short* __restrict__ ysl,
                                                int dup) {
    __shared__ float xs[1024];
    int b = blockIdx.x >> 2;
    int hseg = blockIdx.x & 3;
    int tid = threadIdx.x;
    for (int i = tid; i < 1024; i += 256)
        xs[i] = dup ? xin[b * 512 + (i & 511)] : xin[b * 1024 + i];
    __syncthreads();
    int hidx = hseg * 256 + tid;
    const float* wr = Wih + (size_t)hidx * 1024;
    const float* wz = Wih + (size_t)(Hc + hidx) * 1024;
    const float* wn = Wih + (size_t)(2 * Hc + hidx) * 1024;
    float ar = 0.f, az = 0.f, an = 0.f;
    for (int k = 0; k < 1024; k += 4) {
        float4 x4 = *(const float4*)&xs[k];
        ar += dot4(*(const float4*)&wr[k], x4);
        az += dot4(*(const float4*)&wz[k], x4);
        an += dot4(*(const float4*)&wn[k], x4);
    }
    float r = sigm(ar + bih[hidx] + bhh[hidx]);
    float z = sigm(az + bih[Hc + hidx] + bhh[Hc + hidx]);
    float n = tanhf(an + bih[2 * Hc + hidx] + r * bhh[2 * Hc + hidx]);
    float h = (1.f - z) * n;  // h_old = 0
    h0out[b * Hc + hidx] = h;
    unsigned short hb = f2b(h);
    ysh[b * 1024 + hidx] = hb;
    ysl[b * 1024 + hidx] = f2b(h - b2f(hb));
}

// ---------------------------------------------------------------------------
// MFMA-based 64-step GRU scan. 256 blocks x 64 threads (ONE wave per block).
// Block k owns h-indices [4k,4k+4) = 12 gate-rows (gr = gate*4+hl, gate-major).
// W_hh rows split fp32->bf16 hi/lo ONCE into XOR-swizzled LDS (64 KB).
// Per round t: wave loads the full h[t] slice (16 b x 1024 k, bf16 hi/lo, 8B
// agent-scope atomic loads -- proven r3 path), A-frags (weights) from LDS,
// 4-pass split product over 32 k-tiles: 128 x mfma_f32_16x16x32_bf16.
// D[gr][b] at lane(col=b, row=quad*4+reg); tiny LDS transpose hands all 12
// gate values for batch b to lane b -> fp32 GRU gate math, h_old in regs,
// h[t+1] stored as bf16 hi/lo (8B agent-scope atomic stores).
//
// Inter-block sync (v3, RMW-FREE): each block's lane 0 STORES round-stamp
// t+1 to its OWN flag line (256 lines x 128B, one writer each, monotone ->
// no ABA). Block 0 sweeps all 256 flags (4 atomic loads/lane, parallel L3
// channels) and on success stores t+1 to 16 release lines (<=16 pollers
// each). No atomic RMW anywhere; no polled line receives more than one
// write per round -- removes the root-line RMW-vs-poll queueing that made
// the old tree barrier ~8 us/round. Ordering: h-stores drained by vmcnt(0)
// BEFORE the flag store; release observed -> flags observed -> h visible.
// ---------------------------------------------------------------------------
__global__ __launch_bounds__(64, 1) void gru_scan_mfma(
    const float* __restrict__ xp, const float* __restrict__ Whh,
    const float* __restrict__ bhh, unsigned short* __restrict__ ysh,
    unsigned short* __restrict__ ysl, unsigned* __restrict__ bar) {
    extern __shared__ unsigned short Wlo[];   // [16*1024] 32 KB (dynamic)
    __shared__ unsigned short Whi[16][1024];  // 32 KB
    __shared__ float dxc[16][16];             // D transpose scratch
    const int lane = threadIdx.x;
    const int g0 = blockIdx.x * 4;
    const int brow = lane & 15;  // A-row (gr) for LDS reads, B-row (b) for h
    const int kq = lane >> 4;    // k-quadrant within a 32-wide k-tile

    // stage 12 weight rows (gr = gate*4+hl), split to hi/lo, XOR-swizzled so
    // a-frag ds_read_b128 across rows 0-15 is bank-conflict-free (G4 fix:
    // byte ^= (row&7)<<4; row stride 2048B would otherwise be 16-way).
    for (int i = lane; i < 12 * 256; i += 64) {
        int r = i >> 8, c = i & 255;
        size_t wrow = (size_t)((r >> 2) * Hc + g0 + (r & 3)) * Hc;
        float4 w4 = *(const float4*)&Whh[wrow + c * 4];
        ushort4 h4, l4;
        h4.x = f2b(w4.x); l4.x = f2b(w4.x - b2f(h4.x));
        h4.y = f2b(w4.y); l4.y = f2b(w4.y - b2f(h4.y));
        h4.z = f2b(w4.z); l4.z = f2b(w4.z - b2f(h4.z));
        h4.w = f2b(w4.w); l4.w = f2b(w4.w - b2f(h4.w));
        int bo = (c * 8) ^ ((r & 7) << 4);
        *(ushort4*)((char*)&Whi[r][0] + bo) = h4;
        *(ushort4*)((char*)&Wlo[r * 1024] + bo) = l4;
    }
    ushort4 z4 = {0, 0, 0, 0};
    for (int i = lane; i < 4 * 256; i += 64) {  // pad rows 12-15 = 0
        int r = 12 + (i >> 8), c = i & 255;
        ((ushort4*)&Whi[r][0])[c] = z4;
        ((ushort4*)&Wlo[r * 1024])[c] = z4;
    }

    float bh[12];
#pragma unroll
    for (int r = 0; r < 12; ++r) bh[r] = bhh[(r >> 2) * Hc + g0 + (r & 3)];

    // hold init from slot 0 (hi+lo reconstruct), lanes 0-15 use it
    float hold[4];
    {
        const unsigned long long* s0h =
            (const unsigned long long*)ysh + (size_t)brow * 256 + blockIdx.x;
        const unsigned long long* s0l =
            (const unsigned long long*)ysl + (size_t)brow * 256 + blockIdx.x;
        union { unsigned long long u; ushort4 s; } ch, cl;
        ch.u = __hip_atomic_load(s0h, __ATOMIC_RELAXED, __HIP_MEMORY_SCOPE_AGENT);
        cl.u = __hip_atomic_load(s0l, __ATOMIC_RELAXED, __HIP_MEMORY_SCOPE_AGENT);
        hold[0] = b2f(ch.s.x) + b2f(cl.s.x);
        hold[1] = b2f(ch.s.y) + b2f(cl.s.y);
        hold[2] = b2f(ch.s.z) + b2f(cl.s.z);
        hold[3] = b2f(ch.s.w) + b2f(cl.s.w);
    }
    __syncthreads();

    const char* wha = (const char*)&Whi[0][0] + brow * 2048;
    const char* wla = (const char*)Wlo + brow * 2048;
    const int swz = (brow & 7) << 4;

    unsigned* flagbase = bar;          // 256 lines x 128 B (32 u32 apart)
    unsigned* relbase = bar + 8192;    // 16 lines x 128 B

    for (int t = 0; t < Tc; ++t) {
        // B-frag h loads: 32 k-tiles x 16B (hi & lo) via 2x8B agent atomics
        const unsigned long long* bsh =
            (const unsigned long long*)ysh + (size_t)(t * 16 + brow) * 256 + kq * 2;
        const unsigned long long* bsl =
            (const unsigned long long*)ysl + (size_t)(t * 16 + brow) * 256 + kq * 2;
        unsigned long long vh[64], vl[64];
#pragma unroll
        for (int kt = 0; kt < 32; ++kt) {
            vh[kt * 2] = __hip_atomic_load(bsh + kt * 8, __ATOMIC_RELAXED,
                                           __HIP_MEMORY_SCOPE_AGENT);
            vh[kt * 2 + 1] = __hip_atomic_load(bsh + kt * 8 + 1, __ATOMIC_RELAXED,
                                               __HIP_MEMORY_SCOPE_AGENT);
            vl[kt * 2] = __hip_atomic_load(bsl + kt * 8, __ATOMIC_RELAXED,
                                           __HIP_MEMORY_SCOPE_AGENT);
            vl[kt * 2 + 1] = __hip_atomic_load(bsl + kt * 8 + 1, __ATOMIC_RELAXED,
                                               __HIP_MEMORY_SCOPE_AGENT);
        }
        // xp gate values for (t, b) — plain loads (xp static since GEMM)
        const float* xrow = xp + (size_t)(t * 16 + brow) * 3072 + g0;
        f32x4 xgr = *(const f32x4*)&xrow[0];
        f32x4 xgz = *(const f32x4*)&xrow[1024];
        f32x4 xgn = *(const f32x4*)&xrow[2048];

        f32x4 zz = {0.f, 0.f, 0.f, 0.f};
        f32x4 acc[4];
        acc[0] = zz; acc[1] = zz; acc[2] = zz; acc[3] = zz;
#pragma unroll
        for (int kt = 0; kt < 32; ++kt) {
            bf16x8 ah = *(const bf16x8*)(wha + ((kt * 64 + kq * 16) ^ swz));
            bf16x8 al = *(const bf16x8*)(wla + ((kt * 64 + kq * 16) ^ swz));
            union { unsigned long long u[2]; bf16x8 v; } ch, cl;
            ch.u[0] = vh[kt * 2]; ch.u[1] = vh[kt * 2 + 1];
            cl.u[0] = vl[kt * 2]; cl.u[1] = vl[kt * 2 + 1];
            acc[kt & 3] = __builtin_amdgcn_mfma_f32_16x16x32_bf16(ah, ch.v,
                                                                  acc[kt & 3], 0, 0, 0);
            acc[kt & 3] = __builtin_amdgcn_mfma_f32_16x16x32_bf16(ah, cl.v,
                                                                  acc[kt & 3], 0, 0, 0);
            acc[kt & 3] = __builtin_amdgcn_mfma_f32_16x16x32_bf16(al, ch.v,
                                                                  acc[kt & 3], 0, 0, 0);
            acc[kt & 3] = __builtin_amdgcn_mfma_f32_16x16x32_bf16(al, cl.v,
                                                                  acc[kt & 3], 0, 0, 0);
        }
        f32x4 d = acc[0] + acc[1] + acc[2] + acc[3];
        // transpose D[gr][b] -> lane b via LDS (quad q holds gr = q*4+reg)
        if (kq < 3) *(f32x4*)&dxc[brow][kq * 4] = d;
        __syncthreads();  // 1-wave: just lgkmcnt drain

        if (lane < 16) {
            f32x4 ghr = *(const f32x4*)&dxc[lane][0];
            f32x4 ghz = *(const f32x4*)&dxc[lane][4];
            f32x4 ghn = *(const f32x4*)&dxc[lane][8];
            union { unsigned long long u; ushort4 s; } ph, pl;
            float hn4[4];
#pragma unroll
            for (int hl = 0; hl < 4; ++hl) {
                float r_ = sigm(xgr[hl] + ghr[hl] + bh[hl]);
                float z_ = sigm(xgz[hl] + ghz[hl] + bh[4 + hl]);
                float n_ = tanhf(xgn[hl] + r_ * (ghn[hl] + bh[8 + hl]));
                float h = (1.f - z_) * n_ + z_ * hold[hl];
                hold[hl] = h;
                hn4[hl] = h;
            }
            ph.s.x = f2b(hn4[0]); pl.s.x = f2b(hn4[0] - b2f(ph.s.x));
            ph.s.y = f2b(hn4[1]); pl.s.y = f2b(hn4[1] - b2f(ph.s.y));
            ph.s.z = f2b(hn4[2]); pl.s.z = f2b(hn4[2] - b2f(ph.s.z));
            ph.s.w = f2b(hn4[3]); pl.s.w = f2b(hn4[3] - b2f(ph.s.w));
            unsigned long long* dh = (unsigned long long*)ysh +
                                     (size_t)((t + 1) * 16 + lane) * 256 + blockIdx.x;
            unsigned long long* dl = (unsigned long long*)ysl +
                                     (size_t)((t + 1) * 16 + lane) * 256 + blockIdx.x;
            __hip_atomic_store(dh, ph.u, __ATOMIC_RELAXED, __HIP_MEMORY_SCOPE_AGENT);
            __hip_atomic_store(dl, pl.u, __ATOMIC_RELAXED, __HIP_MEMORY_SCOPE_AGENT);
        }

        if (t < Tc - 1) {
            const unsigned tgt = (unsigned)(t + 1);
            asm volatile("s_waitcnt vmcnt(0)" ::: "memory");  // h stores in L3
            if (lane == 0)
                __hip_atomic_store(flagbase + (size_t)blockIdx.x * 32, tgt,
                                   __ATOMIC_RELAXED, __HIP_MEMORY_SCOPE_AGENT);
            if (blockIdx.x == 0) {
                asm volatile("s_waitcnt vmcnt(0)" ::: "memory");  // own flag landed
                for (;;) {
                    bool ok = true;
#pragma unroll
                    for (int j = 0; j < 4; ++j) {
                        unsigned f = __hip_atomic_load(
                            flagbase + (size_t)(lane * 4 + j) * 32, __ATOMIC_RELAXED,
                            __HIP_MEMORY_SCOPE_AGENT);
                        ok &= (f >= tgt);
                    }
                    if (__ballot(ok ? 1 : 0) == ~0ull) break;
                    __builtin_amdgcn_s_sleep(2);
                }
                if (lane < 16)
                    __hip_atomic_store(relbase + (size_t)lane * 32, tgt,
                                       __ATOMIC_RELAXED, __HIP_MEMORY_SCOPE_AGENT);
            }
            while (__hip_atomic_load(relbase + (size_t)(blockIdx.x & 15) * 32,
                                     __ATOMIC_RELAXED,
                                     __HIP_MEMORY_SCOPE_AGENT) < tgt)
                __builtin_amdgcn_s_sleep(1);
            asm volatile("" ::: "memory");
        }
    }
}

// ---------------------------------------------------------------------------
// Split-bf16 MFMA GEMM (fp32-accurate): C = act( A @ B^T + bias ), where
// A = Ah + Al, B = Bh + Bl and C = Ah Bh + Ah Bl + Al Bh (3 phases).
// 128x128 tile, BK=32, 4 waves in 2x2, 16x16x32 bf16 MFMA.
// remap=1: output row m=t*B+b stored at row b*T+t. N edge guarded.
// ---------------------------------------------------------------------------
#define GLD_LDS16(g, l)                                                        \
    __builtin_amdgcn_global_load_lds(                                          \
        (const __attribute__((address_space(1))) unsigned int*)(g),            \
        (__attribute__((address_space(3))) unsigned int*)(l), 16, 0, 0)

__global__ __launch_bounds__(256) void mfma_gemm_split(
    const unsigned short* __restrict__ Ah, const unsigned short* __restrict__ Al,
    const unsigned short* __restrict__ Bh, const unsigned short* __restrict__ Bl,
    const float* __restrict__ bias, float* __restrict__ C, int N, int K, int ldc,
    int act, int remap) {
    __shared__ __align__(16) unsigned short As[128 * 32];  // [m][k] 8 KB
    __shared__ __align__(16) unsigned short Bs[128 * 32];  // [n][k] 8 KB
    int tid = threadIdx.x;
    int m0 = blockIdx.y * 128, n0 = blockIdx.x * 128;
    int wave = tid >> 6, lane = tid & 63;
    int mh = (wave >> 1) * 64, nh = (wave & 1) * 64;
    int rlane = lane & 15, k8 = (lane >> 4) * 8;

    f32x4 zero = {0.f, 0.f, 0.f, 0.f};
    f32x4 acc[4][4];
#pragma unroll
    for (int i = 0; i < 4; ++i)
#pragma unroll
        for (int j = 0; j < 4; ++j) acc[i][j] = zero;

    const unsigned short* Ap[3] = {Ah, Al, Ah};
    const unsigned short* Bp[3] = {Bh, Bh, Bl};

    int c0 = tid, c1 = tid + 256;
    int ar0 = m0 + (c0 >> 2), ak0 = (c0 & 3) * 8;
    int ar1 = m0 + (c1 >> 2), ak1 = (c1 & 3) * 8;
    int br0 = n0 + (c0 >> 2);
    int br1 = n0 + (c1 >> 2);
    if (br0 >= N) br0 = N - 1;
    if (br1 >= N) br1 = N - 1;

    for (int ph = 0; ph < 3; ++ph) {
        const unsigned short* Ab = Ap[ph];
        const unsigned short* Bb = Bp[ph];
        for (int kt = 0; kt < K; kt += 32) {
            GLD_LDS16(&Ab[(size_t)ar0 * K + kt + ak0], &As[c0 * 8]);
            GLD_LDS16(&Ab[(size_t)ar1 * K + kt + ak1], &As[c1 * 8]);
            GLD_LDS16(&Bb[(size_t)br0 * K + kt + ak0], &Bs[c0 * 8]);
            GLD_LDS16(&Bb[(size_t)br1 * K + kt + ak1], &Bs[c1 * 8]);
            __syncthreads();
            bf16x8 a[4], b[4];
#pragma unroll
            for (int f = 0; f < 4; ++f)
                a[f] = *(const bf16x8*)&As[(mh + f * 16 + rlane) * 32 + k8];
#pragma unroll
            for (int f = 0; f < 4; ++f)
                b[f] = *(const bf16x8*)&Bs[(nh + f * 16 + rlane) * 32 + k8];
#pragma unroll
            for (int mf = 0; mf < 4; ++mf)
#pragma unroll
                for (int nf = 0; nf < 4; ++nf)
                    acc[mf][nf] = __builtin_amdgcn_mfma_f32_16x16x32_bf16(
                        a[mf], b[nf], acc[mf][nf], 0, 0, 0);
            __syncthreads();
        }
    }

    int quad = lane >> 4;
#pragma unroll
    for (int nf = 0; nf < 4; ++nf) {
        int n = n0 + nh + nf * 16 + rlane;
        if (n >= N) continue;
        float bv = bias ? bias[n] : 0.f;
#pragma unroll
        for (int mf = 0; mf < 4; ++mf) {
#pragma unroll
            for (int r = 0; r < 4; ++r) {
                int m = m0 + mh + mf * 16 + quad * 4 + r;
                float x = acc[mf][nf][r] + bv;
                if (act) x = tanhf(x);
                int orow = remap ? ((m & 15) * Tc + (m >> 4)) : m;
                C[(size_t)orow * ldc + n] = x;
            }
        }
    }
}

// ---------------------------------------------------------------------------
extern "C" void kernel_launch(void* const* d_in, const int* in_sizes, int n_in,
                              void* d_out, int out_size, void* d_ws, size_t ws_size,
                              hipStream_t stream) {
    const float* init   = (const float*)d_in[0];
    const int*   helper = (const int*)d_in[1];
    const float* emb    = (const float*)d_in[2];
    const float* W_ih0  = (const float*)d_in[3];
    const float* W_hh0  = (const float*)d_in[4];
    const float* b_ih0  = (const float*)d_in[5];
    const float* b_hh0  = (const float*)d_in[6];
    const float* W_ih1  = (const float*)d_in[7];
    const float* W_hh1  = (const float*)d_in[8];
    const float* b_ih1  = (const float*)d_in[9];
    const float* b_hh1  = (const float*)d_in[10];
    const float* Wc_w   = (const float*)d_in[11];
    const float* Wc_b   = (const float*)d_in[12];
    float* out = (float*)d_out;

    const int embN = Vc * Ec;
    const size_t ysN = (size_t)65 * 16 * 1024;  // bf16 elements per ys stream

    char* p = (char*)d_ws;
    auto alloc = [&](size_t bytes) {
        char* r = p;
        p += (bytes + 255) & ~(size_t)255;
        return r;
    };
    float* X0   = (float*)alloc((size_t)1048576 * 4);
    float* xp0  = (float*)alloc((size_t)3145728 * 4);
    float* xp1  = (float*)alloc((size_t)3145728 * 4);
    float* fin  = (float*)alloc((size_t)524288 * 4);
    float* h00  = (float*)alloc((size_t)16384 * 4);
    float* h01  = (float*)alloc((size_t)16384 * 4);
    unsigned* bar = (unsigned*)alloc(131072);  // 2 scan regions x 64 KB
    unsigned short* embh = (unsigned short*)alloc((size_t)embN * 2);
    unsigned short* embl = (unsigned short*)alloc((size_t)embN * 2);
    unsigned short* X0h  = (unsigned short*)alloc((size_t)1048576 * 2);
    unsigned short* X0l  = (unsigned short*)alloc((size_t)1048576 * 2);
    unsigned short* Wi0h = (unsigned short*)alloc((size_t)3145728 * 2);
    unsigned short* Wi0l = (unsigned short*)alloc((size_t)3145728 * 2);
    unsigned short* Wi1h = (unsigned short*)alloc((size_t)3145728 * 2);
    unsigned short* Wi1l = (unsigned short*)alloc((size_t)3145728 * 2);
    unsigned short* Wch  = (unsigned short*)alloc((size_t)524288 * 2);
    unsigned short* Wcl  = (unsigned short*)alloc((size_t)524288 * 2);
    unsigned short* ys0h = (unsigned short*)alloc(ysN * 2);
    unsigned short* ys0l = (unsigned short*)alloc(ysN * 2);
    unsigned short* ys1h = (unsigned short*)alloc(ysN * 2);
    unsigned short* ys1l = (unsigned short*)alloc(ysN * 2);
    unsigned short* finh = (unsigned short*)alloc((size_t)524288 * 2);
    unsigned short* finl = (unsigned short*)alloc((size_t)524288 * 2);

    hipMemsetAsync(bar, 0, 131072, stream);

    auto split = [&](const float* src, unsigned short* h, unsigned short* l, int n) {
        int n4 = n / 4;
        int grid = (n4 + 255) / 256;
        if (grid > 4096) grid = 4096;
        split_bf16_4<<<grid, 256, 0, stream>>>((const float4*)src, (ushort4*)h,
                                               (ushort4*)l, n4);
    };

    split(emb, embh, embl, embN);
    split(W_ih0, Wi0h, Wi0l, 3145728);
    split(W_ih1, Wi1h, Wi1l, 3145728);
    split(Wc_w, Wch, Wcl, 524288);

    // h0 chain: layer0 (fp32 out + ys0 slot 0 hi/lo), layer1 (ys1 slot 0)
    h0_layer<<<64, 256, 0, stream>>>(init, W_ih0, b_ih0, b_hh0, h00, ys0h, ys0l, 1);
    h0_layer<<<64, 256, 0, stream>>>(h00, W_ih1, b_ih1, b_hh1, h01, ys1h, ys1l, 0);

    build_x0<<<1024, 256, 0, stream>>>(emb, helper, init, X0);
    split(X0, X0h, X0l, 1048576);
    mfma_gemm_split<<<dim3(24, 8), 256, 0, stream>>>(X0h, X0l, Wi0h, Wi0l, b_ih0,
                                                     xp0, 3072, 1024, 3072, 0, 0);

    // layer-0 scan (MFMA recurrent MAC, emits ys0 hi/lo directly)
    gru_scan_mfma<<<SCAN_BLOCKS, 64, 32768, stream>>>(xp0, W_hh0, b_hh0, ys0h, ys0l,
                                                      bar);

    // xp1 GEMM consumes ys0 hi/lo natively (no split kernel needed)
    mfma_gemm_split<<<dim3(24, 8), 256, 0, stream>>>(ys0h + 16384, ys0l + 16384,
                                                     Wi1h, Wi1l, b_ih1, xp1, 3072,
                                                     1024, 3072, 0, 0);

    gru_scan_mfma<<<SCAN_BLOCKS, 64, 32768, stream>>>(xp1, W_hh1, b_hh1, ys1h, ys1l,
                                                      bar + 16384);

    mfma_gemm_split<<<dim3(4, 8), 256, 0, stream>>>(ys1h + 16384, ys1l + 16384,
                                                    Wch, Wcl, Wc_b, fin, 512, 1024,
                                                    512, 1, 0);

    split(fin, finh, finl, 524288);
    mfma_gemm_split<<<dim3((Vc + 127) / 128, 8), 256, 0, stream>>>(
        finh, finl, embh, embl, nullptr, out, Vc, 512, Vc, 0, 1);
}

// Round 6
// 1872.069 us; speedup vs baseline: 1.2805x; 1.1407x over previous
//
#include <hip/hip_runtime.h>
#include <math.h>

// Problem constants: B=16, T=64, V=50257, E=512, H=1024, L=2
#define Bc 16
#define Tc 64
#define Vc 50257
#define Ec 512
#define Hc 1024
#define SCAN_BLOCKS 256

typedef __attribute__((ext_vector_type(4))) float f32x4;
typedef __attribute__((ext_vector_type(8))) __bf16 bf16x8;

__device__ __forceinline__ float dot4(float4 a, float4 b) {
    return a.x * b.x + a.y * b.y + a.z * b.z + a.w * b.w;
}
__device__ __forceinline__ float sigm(float x) { return 1.0f / (1.0f + expf(-x)); }

// round-to-nearest-even float -> bf16 bits (finite inputs)
__device__ __forceinline__ unsigned short f2b(float f) {
    unsigned u = __float_as_uint(f);
    unsigned r = u + 0x7fffu + ((u >> 16) & 1u);
    return (unsigned short)(r >> 16);
}
__device__ __forceinline__ float b2f(unsigned short b) {
    return __uint_as_float(((unsigned)b) << 16);
}

// ---------------------------------------------------------------------------
// split fp32 -> (hi, lo) bf16 pair, 4 elements/thread
// ---------------------------------------------------------------------------
__global__ __launch_bounds__(256) void split_bf16_4(const float4* __restrict__ x,
                                                    ushort4* __restrict__ hi,
                                                    ushort4* __restrict__ lo, int n4) {
    int i = blockIdx.x * 256 + threadIdx.x;
    for (; i < n4; i += gridDim.x * 256) {
        float4 v = x[i];
        ushort4 h, l;
        h.x = f2b(v.x); l.x = f2b(v.x - b2f(h.x));
        h.y = f2b(v.y); l.y = f2b(v.y - b2f(h.y));
        h.z = f2b(v.z); l.z = f2b(v.z - b2f(h.z));
        h.w = f2b(v.w); l.w = f2b(v.w - b2f(h.w));
        hi[i] = h;
        lo[i] = l;
    }
}

// ---------------------------------------------------------------------------
// Build X0 (T*B, 2E): row m=t*B+b; cols [0,512)=emb[helper[b,t]], [512,1024)=init[b]
// ---------------------------------------------------------------------------
__global__ __launch_bounds__(256) void build_x0(const float* __restrict__ emb,
                                                const int* __restrict__ helper,
                                                const float* __restrict__ init,
                                                float* __restrict__ X0) {
    int idx = blockIdx.x * 256 + threadIdx.x;
    const int total = Tc * Bc * 1024;
    for (int i = idx; i < total; i += gridDim.x * 256) {
        int m = i >> 10;
        int c = i & 1023;
        int t = m >> 4;
        int b = m & 15;
        float v;
        if (c < 512) {
            int w = helper[b * Tc + t];
            v = emb[(size_t)w * Ec + c];
        } else {
            v = init[b * Ec + (c - 512)];
        }
        X0[i] = v;
    }
}

// ---------------------------------------------------------------------------
// h0 one-step GRU with zero initial state. dup=1 -> input row is [init;init].
// Emits fp32 h0 (for chaining) AND bf16 hi/lo into ys slot 0 (for the scan).
// ---------------------------------------------------------------------------
__global__ __launch_bounds__(256) void h0_layer(const float* __restrict__ xin,
                                                const float* __restrict__ Wih,
                                                const float* __restrict__ bih,
                                                const float* __restrict__ bhh,
                                                float* __restrict__ h0out,
                                                unsigned short* __restrict__ ysh,
                                                unsigned short* __restrict__ ysl,
                                                int dup) {
    __shared__ float xs[1024];
    int b = blockIdx.x >> 2;
    int hseg = blockIdx.x & 3;
    int tid = threadIdx.x;
    for (int i = tid; i < 1024; i += 256)
        xs[i] = dup ? xin[b * 512 + (i & 511)] : xin[b * 1024 + i];
    __syncthreads();
    int hidx = hseg * 256 + tid;
    const float* wr = Wih + (size_t)hidx * 1024;
    const float* wz = Wih + (size_t)(Hc + hidx) * 1024;
    const float* wn = Wih + (size_t)(2 * Hc + hidx) * 1024;
    float ar = 0.f, az = 0.f, an = 0.f;
    for (int k = 0; k < 1024; k += 4) {
        float4 x4 = *(const float4*)&xs[k];
        ar += dot4(*(const float4*)&wr[k], x4);
        az += dot4(*(const float4*)&wz[k], x4);
        an += dot4(*(const float4*)&wn[k], x4);
    }
    float r = sigm(ar + bih[hidx] + bhh[hidx]);
    float z = sigm(az + bih[Hc + hidx] + bhh[Hc + hidx]);
    float n = tanhf(an + bih[2 * Hc + hidx] + r * bhh[2 * Hc + hidx]);
    float h = (1.f - z) * n;  // h_old = 0
    h0out[b * Hc + hidx] = h;
    unsigned short hb = f2b(h);
    ysh[b * 1024 + hidx] = hb;
    ysl[b * 1024 + hidx] = f2b(h - b2f(hb));
}

// ---------------------------------------------------------------------------
// MFMA-based 64-step GRU scan. 256 blocks x 64 threads (ONE wave per block).
// Block k owns h-indices [4k,4k+4) = 12 gate-rows (gr = gate*4+hl, gate-major).
// W_hh rows split fp32->bf16 hi/lo ONCE into XOR-swizzled LDS (64 KB).
//
// h exchange (v4, DENSE-PACKED): in addition to the row-major ysh/ysl copies
// (consumed by the downstream GEMMs), h[t] circulates through a dense array
// ysd of 8B items laid out so each load instruction's 64 lanes cover a fully
// CONTIGUOUS 512 B span (100% L3 granule utilization; the old row-major
// pattern was 16B-strided -> 50%, doubling internal L3 traffic):
//   item(t, kt, p, kq, b) at u64 offset ((t*32+kt)*4+p)*64 + kq*16 + b
//   p in {0,1}: hi bf16 of k = kt*32+kq*8+{0..3, 4..7}; p in {2,3}: lo.
// Producer block c (lane b<16) owns k=4c..4c+3: kt=c>>3, kq=(c>>1)&3, p=c&1
// (hi) / 2+(c&1) (lo). Round t=0 reads the row-major slot 0 (from h0_layer).
//
// Per round: 128 x mfma_f32_16x16x32_bf16 (4-pass hi/lo split, fp32-grade),
// D transpose via LDS, fp32 gate math on lanes<16, h_old in regs.
// Inter-block sync (proven r5): RMW-free flag/sweep/release barrier --
// per-block flag stores (one writer/line), block 0 sweeps 256 flags, fans
// out to 16 release lines. vmcnt(0) drains h stores BEFORE the flag store.
// ---------------------------------------------------------------------------
__global__ __launch_bounds__(64, 1) void gru_scan_mfma(
    const float* __restrict__ xp, const float* __restrict__ Whh,
    const float* __restrict__ bhh, unsigned short* __restrict__ ysh,
    unsigned short* __restrict__ ysl, unsigned long long* __restrict__ ysd,
    unsigned* __restrict__ bar) {
    extern __shared__ unsigned short Wlo[];   // [16*1024] 32 KB (dynamic)
    __shared__ unsigned short Whi[16][1024];  // 32 KB
    __shared__ float dxc[16][16];             // D transpose scratch
    const int lane = threadIdx.x;
    const int g0 = blockIdx.x * 4;
    const int brow = lane & 15;  // A-row (gr) for LDS reads, B-row (b) for h
    const int kq = lane >> 4;    // k-quadrant within a 32-wide k-tile

    // stage 12 weight rows (gr = gate*4+hl), split to hi/lo, XOR-swizzled so
    // a-frag ds_read_b128 across rows 0-15 is bank-conflict-free (G4 fix:
    // byte ^= (row&7)<<4; row stride 2048B would otherwise be 16-way).
    for (int i = lane; i < 12 * 256; i += 64) {
        int r = i >> 8, c = i & 255;
        size_t wrow = (size_t)((r >> 2) * Hc + g0 + (r & 3)) * Hc;
        float4 w4 = *(const float4*)&Whh[wrow + c * 4];
        ushort4 h4, l4;
        h4.x = f2b(w4.x); l4.x = f2b(w4.x - b2f(h4.x));
        h4.y = f2b(w4.y); l4.y = f2b(w4.y - b2f(h4.y));
        h4.z = f2b(w4.z); l4.z = f2b(w4.z - b2f(h4.z));
        h4.w = f2b(w4.w); l4.w = f2b(w4.w - b2f(h4.w));
        int bo = (c * 8) ^ ((r & 7) << 4);
        *(ushort4*)((char*)&Whi[r][0] + bo) = h4;
        *(ushort4*)((char*)&Wlo[r * 1024] + bo) = l4;
    }
    ushort4 z4 = {0, 0, 0, 0};
    for (int i = lane; i < 4 * 256; i += 64) {  // pad rows 12-15 = 0
        int r = 12 + (i >> 8), c = i & 255;
        ((ushort4*)&Whi[r][0])[c] = z4;
        ((ushort4*)&Wlo[r * 1024])[c] = z4;
    }

    float bh[12];
#pragma unroll
    for (int r = 0; r < 12; ++r) bh[r] = bhh[(r >> 2) * Hc + g0 + (r & 3)];

    // hold init from slot 0 (hi+lo reconstruct), lanes 0-15 use it
    float hold[4];
    {
        const unsigned long long* s0h =
            (const unsigned long long*)ysh + (size_t)brow * 256 + blockIdx.x;
        const unsigned long long* s0l =
            (const unsigned long long*)ysl + (size_t)brow * 256 + blockIdx.x;
        union { unsigned long long u; ushort4 s; } ch, cl;
        ch.u = __hip_atomic_load(s0h, __ATOMIC_RELAXED, __HIP_MEMORY_SCOPE_AGENT);
        cl.u = __hip_atomic_load(s0l, __ATOMIC_RELAXED, __HIP_MEMORY_SCOPE_AGENT);
        hold[0] = b2f(ch.s.x) + b2f(cl.s.x);
        hold[1] = b2f(ch.s.y) + b2f(cl.s.y);
        hold[2] = b2f(ch.s.z) + b2f(cl.s.z);
        hold[3] = b2f(ch.s.w) + b2f(cl.s.w);
    }
    __syncthreads();

    const char* wha = (const char*)&Whi[0][0] + brow * 2048;
    const char* wla = (const char*)Wlo + brow * 2048;
    const int swz = (brow & 7) << 4;

    unsigned* flagbase = bar;          // 256 lines x 128 B (32 u32 apart)
    unsigned* relbase = bar + 8192;    // 16 lines x 128 B

    // dense-store address for this block (lane<16 path): hi at +0, lo at +128
    const size_t dstoff = (size_t)(blockIdx.x >> 3) * 256 +
                          (size_t)(blockIdx.x & 1) * 64 +
                          (size_t)((blockIdx.x >> 1) & 3) * 16 + lane;

    for (int t = 0; t < Tc; ++t) {
        unsigned long long vh[64], vl[64];
        if (t == 0) {
            // row-major slot 0 (written by h0_layer): 16B-strided pattern
            const unsigned long long* bsh =
                (const unsigned long long*)ysh + (size_t)brow * 256 + kq * 2;
            const unsigned long long* bsl =
                (const unsigned long long*)ysl + (size_t)brow * 256 + kq * 2;
#pragma unroll
            for (int kt = 0; kt < 32; ++kt) {
                vh[kt * 2] = __hip_atomic_load(bsh + kt * 8, __ATOMIC_RELAXED,
                                               __HIP_MEMORY_SCOPE_AGENT);
                vh[kt * 2 + 1] = __hip_atomic_load(bsh + kt * 8 + 1, __ATOMIC_RELAXED,
                                                   __HIP_MEMORY_SCOPE_AGENT);
                vl[kt * 2] = __hip_atomic_load(bsl + kt * 8, __ATOMIC_RELAXED,
                                               __HIP_MEMORY_SCOPE_AGENT);
                vl[kt * 2 + 1] = __hip_atomic_load(bsl + kt * 8 + 1, __ATOMIC_RELAXED,
                                                   __HIP_MEMORY_SCOPE_AGENT);
            }
        } else {
            // dense layout: each instruction's 64 lanes cover 512B contiguous
            const unsigned long long* dsrc =
                ysd + (size_t)t * 8192 + kq * 16 + brow;
#pragma unroll
            for (int kt = 0; kt < 32; ++kt) {
                vh[kt * 2] = __hip_atomic_load(dsrc + kt * 256, __ATOMIC_RELAXED,
                                               __HIP_MEMORY_SCOPE_AGENT);
                vh[kt * 2 + 1] = __hip_atomic_load(dsrc + kt * 256 + 64,
                                                   __ATOMIC_RELAXED,
                                                   __HIP_MEMORY_SCOPE_AGENT);
                vl[kt * 2] = __hip_atomic_load(dsrc + kt * 256 + 128,
                                               __ATOMIC_RELAXED,
                                               __HIP_MEMORY_SCOPE_AGENT);
                vl[kt * 2 + 1] = __hip_atomic_load(dsrc + kt * 256 + 192,
                                                   __ATOMIC_RELAXED,
                                                   __HIP_MEMORY_SCOPE_AGENT);
            }
        }
        // xp gate values for (t, b) — plain loads (xp static since GEMM)
        const float* xrow = xp + (size_t)(t * 16 + brow) * 3072 + g0;
        f32x4 xgr = *(const f32x4*)&xrow[0];
        f32x4 xgz = *(const f32x4*)&xrow[1024];
        f32x4 xgn = *(const f32x4*)&xrow[2048];

        f32x4 zz = {0.f, 0.f, 0.f, 0.f};
        f32x4 acc[4];
        acc[0] = zz; acc[1] = zz; acc[2] = zz; acc[3] = zz;
#pragma unroll
        for (int kt = 0; kt < 32; ++kt) {
            bf16x8 ah = *(const bf16x8*)(wha + ((kt * 64 + kq * 16) ^ swz));
            bf16x8 al = *(const bf16x8*)(wla + ((kt * 64 + kq * 16) ^ swz));
            union { unsigned long long u[2]; bf16x8 v; } ch, cl;
            ch.u[0] = vh[kt * 2]; ch.u[1] = vh[kt * 2 + 1];
            cl.u[0] = vl[kt * 2]; cl.u[1] = vl[kt * 2 + 1];
            acc[kt & 3] = __builtin_amdgcn_mfma_f32_16x16x32_bf16(ah, ch.v,
                                                                  acc[kt & 3], 0, 0, 0);
            acc[kt & 3] = __builtin_amdgcn_mfma_f32_16x16x32_bf16(ah, cl.v,
                                                                  acc[kt & 3], 0, 0, 0);
            acc[kt & 3] = __builtin_amdgcn_mfma_f32_16x16x32_bf16(al, ch.v,
                                                                  acc[kt & 3], 0, 0, 0);
            acc[kt & 3] = __builtin_amdgcn_mfma_f32_16x16x32_bf16(al, cl.v,
                                                                  acc[kt & 3], 0, 0, 0);
        }
        f32x4 d = acc[0] + acc[1] + acc[2] + acc[3];
        // transpose D[gr][b] -> lane b via LDS (quad q holds gr = q*4+reg)
        if (kq < 3) *(f32x4*)&dxc[brow][kq * 4] = d;
        __syncthreads();  // 1-wave: just lgkmcnt drain

        if (lane < 16) {
            f32x4 ghr = *(const f32x4*)&dxc[lane][0];
            f32x4 ghz = *(const f32x4*)&dxc[lane][4];
            f32x4 ghn = *(const f32x4*)&dxc[lane][8];
            union { unsigned long long u; ushort4 s; } ph, pl;
            float hn4[4];
#pragma unroll
            for (int hl = 0; hl < 4; ++hl) {
                float r_ = sigm(xgr[hl] + ghr[hl] + bh[hl]);
                float z_ = sigm(xgz[hl] + ghz[hl] + bh[4 + hl]);
                float n_ = tanhf(xgn[hl] + r_ * (ghn[hl] + bh[8 + hl]));
                float h = (1.f - z_) * n_ + z_ * hold[hl];
                hold[hl] = h;
                hn4[hl] = h;
            }
            ph.s.x = f2b(hn4[0]); pl.s.x = f2b(hn4[0] - b2f(ph.s.x));
            ph.s.y = f2b(hn4[1]); pl.s.y = f2b(hn4[1] - b2f(ph.s.y));
            ph.s.z = f2b(hn4[2]); pl.s.z = f2b(hn4[2] - b2f(ph.s.z));
            ph.s.w = f2b(hn4[3]); pl.s.w = f2b(hn4[3] - b2f(ph.s.w));
            // row-major copies (consumed by downstream GEMMs)
            unsigned long long* dh = (unsigned long long*)ysh +
                                     (size_t)((t + 1) * 16 + lane) * 256 + blockIdx.x;
            unsigned long long* dl = (unsigned long long*)ysl +
                                     (size_t)((t + 1) * 16 + lane) * 256 + blockIdx.x;
            __hip_atomic_store(dh, ph.u, __ATOMIC_RELAXED, __HIP_MEMORY_SCOPE_AGENT);
            __hip_atomic_store(dl, pl.u, __ATOMIC_RELAXED, __HIP_MEMORY_SCOPE_AGENT);
            // dense copy (consumed by next scan round)
            unsigned long long* dd = ysd + (size_t)(t + 1) * 8192 + dstoff;
            __hip_atomic_store(dd, ph.u, __ATOMIC_RELAXED, __HIP_MEMORY_SCOPE_AGENT);
            __hip_atomic_store(dd + 128, pl.u, __ATOMIC_RELAXED,
                               __HIP_MEMORY_SCOPE_AGENT);
        }

        if (t < Tc - 1) {
            const unsigned tgt = (unsigned)(t + 1);
            asm volatile("s_waitcnt vmcnt(0)" ::: "memory");  // h stores in L3
            if (lane == 0)
                __hip_atomic_store(flagbase + (size_t)blockIdx.x * 32, tgt,
                                   __ATOMIC_RELAXED, __HIP_MEMORY_SCOPE_AGENT);
            if (blockIdx.x == 0) {
                asm volatile("s_waitcnt vmcnt(0)" ::: "memory");  // own flag landed
                for (;;) {
                    bool ok = true;
#pragma unroll
                    for (int j = 0; j < 4; ++j) {
                        unsigned f = __hip_atomic_load(
                            flagbase + (size_t)(lane * 4 + j) * 32, __ATOMIC_RELAXED,
                            __HIP_MEMORY_SCOPE_AGENT);
                        ok &= (f >= tgt);
                    }
                    if (__ballot(ok ? 1 : 0) == ~0ull) break;
                    __builtin_amdgcn_s_sleep(2);
                }
                if (lane < 16)
                    __hip_atomic_store(relbase + (size_t)lane * 32, tgt,
                                       __ATOMIC_RELAXED, __HIP_MEMORY_SCOPE_AGENT);
            }
            while (__hip_atomic_load(relbase + (size_t)(blockIdx.x & 15) * 32,
                                     __ATOMIC_RELAXED,
                                     __HIP_MEMORY_SCOPE_AGENT) < tgt)
                __builtin_amdgcn_s_sleep(1);
            asm volatile("" ::: "memory");
        }
    }
}

// ---------------------------------------------------------------------------
// Split-bf16 MFMA GEMM (fp32-accurate): C = act( A @ B^T + bias ), where
// A = Ah + Al, B = Bh + Bl and C = Ah Bh + Ah Bl + Al Bh (3 phases).
// 128x128 tile, BK=32, 4 waves in 2x2, 16x16x32 bf16 MFMA.
// remap=1: output row m=t*B+b stored at row b*T+t. N edge guarded.
// ---------------------------------------------------------------------------
#define GLD_LDS16(g, l)                                                        \
    __builtin_amdgcn_global_load_lds(                                          \
        (const __attribute__((address_space(1))) unsigned int*)(g),            \
        (__attribute__((address_space(3))) unsigned int*)(l), 16, 0, 0)

__global__ __launch_bounds__(256) void mfma_gemm_split(
    const unsigned short* __restrict__ Ah, const unsigned short* __restrict__ Al,
    const unsigned short* __restrict__ Bh, const unsigned short* __restrict__ Bl,
    const float* __restrict__ bias, float* __restrict__ C, int N, int K, int ldc,
    int act, int remap) {
    __shared__ __align__(16) unsigned short As[128 * 32];  // [m][k] 8 KB
    __shared__ __align__(16) unsigned short Bs[128 * 32];  // [n][k] 8 KB
    int tid = threadIdx.x;
    int m0 = blockIdx.y * 128, n0 = blockIdx.x * 128;
    int wave = tid >> 6, lane = tid & 63;
    int mh = (wave >> 1) * 64, nh = (wave & 1) * 64;
    int rlane = lane & 15, k8 = (lane >> 4) * 8;

    f32x4 zero = {0.f, 0.f, 0.f, 0.f};
    f32x4 acc[4][4];
#pragma unroll
    for (int i = 0; i < 4; ++i)
#pragma unroll
        for (int j = 0; j < 4; ++j) acc[i][j] = zero;

    const unsigned short* Ap[3] = {Ah, Al, Ah};
    const unsigned short* Bp[3] = {Bh, Bh, Bl};

    int c0 = tid, c1 = tid + 256;
    int ar0 = m0 + (c0 >> 2), ak0 = (c0 & 3) * 8;
    int ar1 = m0 + (c1 >> 2), ak1 = (c1 & 3) * 8;
    int br0 = n0 + (c0 >> 2);
    int br1 = n0 + (c1 >> 2);
    if (br0 >= N) br0 = N - 1;
    if (br1 >= N) br1 = N - 1;

    for (int ph = 0; ph < 3; ++ph) {
        const unsigned short* Ab = Ap[ph];
        const unsigned short* Bb = Bp[ph];
        for (int kt = 0; kt < K; kt += 32) {
            GLD_LDS16(&Ab[(size_t)ar0 * K + kt + ak0], &As[c0 * 8]);
            GLD_LDS16(&Ab[(size_t)ar1 * K + kt + ak1], &As[c1 * 8]);
            GLD_LDS16(&Bb[(size_t)br0 * K + kt + ak0], &Bs[c0 * 8]);
            GLD_LDS16(&Bb[(size_t)br1 * K + kt + ak1], &Bs[c1 * 8]);
            __syncthreads();
            bf16x8 a[4], b[4];
#pragma unroll
            for (int f = 0; f < 4; ++f)
                a[f] = *(const bf16x8*)&As[(mh + f * 16 + rlane) * 32 + k8];
#pragma unroll
            for (int f = 0; f < 4; ++f)
                b[f] = *(const bf16x8*)&Bs[(nh + f * 16 + rlane) * 32 + k8];
#pragma unroll
            for (int mf = 0; mf < 4; ++mf)
#pragma unroll
                for (int nf = 0; nf < 4; ++nf)
                    acc[mf][nf] = __builtin_amdgcn_mfma_f32_16x16x32_bf16(
                        a[mf], b[nf], acc[mf][nf], 0, 0, 0);
            __syncthreads();
        }
    }

    int quad = lane >> 4;
#pragma unroll
    for (int nf = 0; nf < 4; ++nf) {
        int n = n0 + nh + nf * 16 + rlane;
        if (n >= N) continue;
        float bv = bias ? bias[n] : 0.f;
#pragma unroll
        for (int mf = 0; mf < 4; ++mf) {
#pragma unroll
            for (int r = 0; r < 4; ++r) {
                int m = m0 + mh + mf * 16 + quad * 4 + r;
                float x = acc[mf][nf][r] + bv;
                if (act) x = tanhf(x);
                int orow = remap ? ((m & 15) * Tc + (m >> 4)) : m;
                C[(size_t)orow * ldc + n] = x;
            }
        }
    }
}

// ---------------------------------------------------------------------------
extern "C" void kernel_launch(void* const* d_in, const int* in_sizes, int n_in,
                              void* d_out, int out_size, void* d_ws, size_t ws_size,
                              hipStream_t stream) {
    const float* init   = (const float*)d_in[0];
    const int*   helper = (const int*)d_in[1];
    const float* emb    = (const float*)d_in[2];
    const float* W_ih0  = (const float*)d_in[3];
    const float* W_hh0  = (const float*)d_in[4];
    const float* b_ih0  = (const float*)d_in[5];
    const float* b_hh0  = (const float*)d_in[6];
    const float* W_ih1  = (const float*)d_in[7];
    const float* W_hh1  = (const float*)d_in[8];
    const float* b_ih1  = (const float*)d_in[9];
    const float* b_hh1  = (const float*)d_in[10];
    const float* Wc_w   = (const float*)d_in[11];
    const float* Wc_b   = (const float*)d_in[12];
    float* out = (float*)d_out;

    const int embN = Vc * Ec;
    const size_t ysN = (size_t)65 * 16 * 1024;  // bf16 elements per ys stream

    char* p = (char*)d_ws;
    auto alloc = [&](size_t bytes) {
        char* r = p;
        p += (bytes + 255) & ~(size_t)255;
        return r;
    };
    float* X0   = (float*)alloc((size_t)1048576 * 4);
    float* xp0  = (float*)alloc((size_t)3145728 * 4);
    float* xp1  = (float*)alloc((size_t)3145728 * 4);
    float* fin  = (float*)alloc((size_t)524288 * 4);
    float* h00  = (float*)alloc((size_t)16384 * 4);
    float* h01  = (float*)alloc((size_t)16384 * 4);
    unsigned* bar = (unsigned*)alloc(131072);  // 2 scan regions x 64 KB
    unsigned long long* ysd0 = (unsigned long long*)alloc((size_t)65 * 65536);
    unsigned long long* ysd1 = (unsigned long long*)alloc((size_t)65 * 65536);
    unsigned short* embh = (unsigned short*)alloc((size_t)embN * 2);
    unsigned short* embl = (unsigned short*)alloc((size_t)embN * 2);
    unsigned short* X0h  = (unsigned short*)alloc((size_t)1048576 * 2);
    unsigned short* X0l  = (unsigned short*)alloc((size_t)1048576 * 2);
    unsigned short* Wi0h = (unsigned short*)alloc((size_t)3145728 * 2);
    unsigned short* Wi0l = (unsigned short*)alloc((size_t)3145728 * 2);
    unsigned short* Wi1h = (unsigned short*)alloc((size_t)3145728 * 2);
    unsigned short* Wi1l = (unsigned short*)alloc((size_t)3145728 * 2);
    unsigned short* Wch  = (unsigned short*)alloc((size_t)524288 * 2);
    unsigned short* Wcl  = (unsigned short*)alloc((size_t)524288 * 2);
    unsigned short* ys0h = (unsigned short*)alloc(ysN * 2);
    unsigned short* ys0l = (unsigned short*)alloc(ysN * 2);
    unsigned short* ys1h = (unsigned short*)alloc(ysN * 2);
    unsigned short* ys1l = (unsigned short*)alloc(ysN * 2);
    unsigned short* finh = (unsigned short*)alloc((size_t)524288 * 2);
    unsigned short* finl = (unsigned short*)alloc((size_t)524288 * 2);

    hipMemsetAsync(bar, 0, 131072, stream);

    auto split = [&](const float* src, unsigned short* h, unsigned short* l, int n) {
        int n4 = n / 4;
        int grid = (n4 + 255) / 256;
        if (grid > 4096) grid = 4096;
        split_bf16_4<<<grid, 256, 0, stream>>>((const float4*)src, (ushort4*)h,
                                               (ushort4*)l, n4);
    };

    split(emb, embh, embl, embN);
    split(W_ih0, Wi0h, Wi0l, 3145728);
    split(W_ih1, Wi1h, Wi1l, 3145728);
    split(Wc_w, Wch, Wcl, 524288);

    // h0 chain: layer0 (fp32 out + ys0 slot 0 hi/lo), layer1 (ys1 slot 0)
    h0_layer<<<64, 256, 0, stream>>>(init, W_ih0, b_ih0, b_hh0, h00, ys0h, ys0l, 1);
    h0_layer<<<64, 256, 0, stream>>>(h00, W_ih1, b_ih1, b_hh1, h01, ys1h, ys1l, 0);

    build_x0<<<1024, 256, 0, stream>>>(emb, helper, init, X0);
    split(X0, X0h, X0l, 1048576);
    mfma_gemm_split<<<dim3(24, 8), 256, 0, stream>>>(X0h, X0l, Wi0h, Wi0l, b_ih0,
                                                     xp0, 3072, 1024, 3072, 0, 0);

    // layer-0 scan (MFMA recurrent MAC, emits ys0 hi/lo + dense ysd0)
    gru_scan_mfma<<<SCAN_BLOCKS, 64, 32768, stream>>>(xp0, W_hh0, b_hh0, ys0h, ys0l,
                                                      ysd0, bar);

    // xp1 GEMM consumes ys0 hi/lo natively (no split kernel needed)
    mfma_gemm_split<<<dim3(24, 8), 256, 0, stream>>>(ys0h + 16384, ys0l + 16384,
                                                     Wi1h, Wi1l, b_ih1, xp1, 3072,
                                                     1024, 3072, 0, 0);

    gru_scan_mfma<<<SCAN_BLOCKS, 64, 32768, stream>>>(xp1, W_hh1, b_hh1, ys1h, ys1l,
                                                      ysd1, bar + 16384);

    mfma_gemm_split<<<dim3(4, 8), 256, 0, stream>>>(ys1h + 16384, ys1l + 16384,
                                                    Wch, Wcl, Wc_b, fin, 512, 1024,
                                                    512, 1, 0);

    split(fin, finh, finl, 524288);
    mfma_gemm_split<<<dim3((Vc + 127) / 128, 8), 256, 0, stream>>>(
        finh, finl, embh, embl, nullptr, out, Vc, 512, Vc, 0, 1);
}